// Round 3
// baseline (259.471 us; speedup 1.0000x reference)
//
#include <hip/hip_runtime.h>
#include <math.h>

// Folded model (exact algebra, per-token):
//   h      = relu(x @ G1 + b11)                      [400 MACs]
//   g      = relu(h @ P1 + x @ P2 + f2)              [800 MACs]
//   logits = g @ M2 + h @ Q1 + x @ Q2 + f3           [180 MACs]
//   out    = softmax(logits)
// Logits weights stored TRANSPOSED and c-padded to 4 (M2T/Q1T/Q2T: [20][4])
// so loop1/2/3 read one v4 per k for the logits contribution.

// d_ws layout (float offsets), 16B-aligned rows
#define OFF_G1   0      // [20][20] k-major
#define OFF_P1   400    // [20][20] m'-major
#define OFF_P2   800    // [20][20] k-major
#define OFF_M2T  1200   // [20][4]  M2T[m][c] = sum_p Wc[c][p]*W2_1[p][m]
#define OFF_Q1T  1280   // [20][4]  Q1T[k][c]
#define OFF_Q2T  1360   // [20][4]  Q2T[k][c]
#define OFF_B11  1440   // [20]
#define OFF_F2   1460   // [20]
#define OFF_F3   1480   // [3] + pad
#define NWTOT    1484

__global__ void prep_kernel(const float* __restrict__ Wv, const float* __restrict__ Wres,
                            const float* __restrict__ W1, const float* __restrict__ b1,
                            const float* __restrict__ W2, const float* __restrict__ b2,
                            const float* __restrict__ W3, const float* __restrict__ b3,
                            const float* __restrict__ Wc, const float* __restrict__ bc,
                            float* __restrict__ W) {
    __shared__ float G2[400];   // [i][m]
    __shared__ float M3[60];    // [i][c]
    __shared__ float e1[20];
    const int tid = threadIdx.x;
    // ---- phase A: layer-1 folds ----
    for (int idx = tid; idx < 480; idx += 256) {
        if (idx < 400) {
            const int i = idx / 20, m = idx % 20;
            float s = 0.f;
            for (int j = 0; j < 20; ++j)
                s = fmaf(Wv[400 + j*20 + i] + Wres[400 + i*20 + j], W1[400 + m*20 + j], s);
            G2[idx] = s;
        } else if (idx < 460) {
            const int r = idx - 400, i = r / 3, c = r % 3;
            float s = 0.f;
            for (int p = 0; p < 20; ++p)
                s = fmaf(Wc[c*20 + p], W3[400 + p*20 + i], s);
            M3[r] = s;
        } else {
            const int j = idx - 460;
            e1[j] = b2[j] + b3[j];
        }
    }
    __syncthreads();
    // ---- phase B: final folded weights → d_ws ----
    for (int idx = tid; idx < NWTOT; idx += 256) {
        float s = 0.f;
        if (idx < 400) {                       // G1[k][m]
            const int k = idx / 20, m = idx % 20;
            for (int j = 0; j < 20; ++j)
                s = fmaf(Wv[j*20 + k] + Wres[k*20 + j], W1[m*20 + j], s);
        } else if (idx < 800) {                // P1[m'][m]
            const int r = idx - 400, mp = r / 20, m = r % 20;
            for (int i = 0; i < 20; ++i)
                s = fmaf(W2[i*20 + mp], G2[i*20 + m], s);
        } else if (idx < 1200) {               // P2[k][m]
            const int r = idx - 800, k = r / 20, m = r % 20;
            for (int i = 0; i < 20; ++i)
                s = fmaf(W3[i*20 + k], G2[i*20 + m], s);
        } else if (idx < 1280) {               // M2T[m][c]
            const int r = idx - 1200, m = r / 4, c = r % 4;
            if (c < 3)
                for (int p = 0; p < 20; ++p)
                    s = fmaf(Wc[c*20 + p], W2[400 + p*20 + m], s);
        } else if (idx < 1360) {               // Q1T[k][c]
            const int r = idx - 1280, k = r / 4, c = r % 4;
            if (c < 3)
                for (int i = 0; i < 20; ++i)
                    s = fmaf(W2[i*20 + k], M3[i*3 + c], s);
        } else if (idx < 1440) {               // Q2T[k][c]
            const int r = idx - 1360, k = r / 4, c = r % 4;
            if (c < 3)
                for (int i = 0; i < 20; ++i)
                    s = fmaf(W3[i*20 + k], M3[i*3 + c], s);
        } else if (idx < 1460) {               // b11
            s = b1[idx - 1440];
        } else if (idx < 1480) {               // f2
            const int m = idx - 1460;
            s = b1[20 + m];
            for (int i = 0; i < 20; ++i)
                s = fmaf(e1[i], G2[i*20 + m], s);
        } else {                               // f3 (+1 pad = 0)
            const int c = idx - 1480;
            if (c < 3) {
                s = bc[c];
                for (int p = 0; p < 20; ++p)
                    s = fmaf(Wc[c*20 + p], b2[20 + p] + b3[20 + p], s);
                for (int i = 0; i < 20; ++i)
                    s = fmaf(e1[i], M3[i*3 + c], s);
            }
        }
        W[idx] = s;
    }
}

// T=4 tokens/thread: every uniform LDS weight broadcast (ds_read_b128, one
// wave-instr) feeds 16 FMAs (4 tokens x 4 weights) — 4x less weight-fetch
// pressure than T=2, 16x less than T=1-SMEM. Fused low-liveness schedule:
// loop1 consumes x chunk-wise (16 regs) while building h, g(=x@P2 part) and
// la(=x@Q2 part); x never fully live alongside h+g. Peak state ~190 VGPRs,
// legal under (256,2). Loops 2/3 fully unrolled (runtime-indexed register
// arrays would go to scratch); loop1 rolled over q (q never indexes a
// register array) to keep code under the 32KB I$.
typedef float v4f __attribute__((ext_vector_type(4)));

__global__ __launch_bounds__(256, 2) void fwd_kernel(const float* __restrict__ X,
                                                     const float* __restrict__ Wg,
                                                     float* __restrict__ out, int ntok) {
    __shared__ float Ws[NWTOT];
    for (int i = threadIdx.x; i < NWTOT; i += 256) Ws[i] = Wg[i];
    __syncthreads();
    const v4f* W4 = reinterpret_cast<const v4f*>(Ws);

    const int t0 = (blockIdx.x * 256 + threadIdx.x) * 4;
    if (t0 >= ntok) return;
    const float4* xp = reinterpret_cast<const float4*>(X + (size_t)t0 * 20);

    float h[4][20], g[4][20], la[4][3];

    // init: h=b11, g=f2, la=f3 (broadcast to 4 tokens)
    #pragma unroll
    for (int q = 0; q < 5; ++q) {
        const v4f b = W4[OFF_B11/4 + q];
        const v4f f = W4[OFF_F2/4 + q];
        #pragma unroll
        for (int j = 0; j < 4; ++j) {
            h[j][4*q+0] = b.x; h[j][4*q+1] = b.y; h[j][4*q+2] = b.z; h[j][4*q+3] = b.w;
            g[j][4*q+0] = f.x; g[j][4*q+1] = f.y; g[j][4*q+2] = f.z; g[j][4*q+3] = f.w;
        }
    }
    {
        const v4f f3v = W4[OFF_F3/4];
        #pragma unroll
        for (int j = 0; j < 4; ++j) { la[j][0] = f3v.x; la[j][1] = f3v.y; la[j][2] = f3v.z; }
    }

    // ---- loop1 (rolled over q): h += x@G1 ; g += x@P2 ; la += x@Q2T ----
    #pragma unroll 1
    for (int q = 0; q < 5; ++q) {
        float xc[4][4];
        #pragma unroll
        for (int j = 0; j < 4; ++j) {
            const float4 v = xp[j*5 + q];
            xc[j][0] = v.x; xc[j][1] = v.y; xc[j][2] = v.z; xc[j][3] = v.w;
        }
        #pragma unroll
        for (int d = 0; d < 4; ++d) {
            const int k = 4*q + d;
            const v4f wq2 = W4[OFF_Q2T/4 + k];
            #pragma unroll
            for (int j = 0; j < 4; ++j) {
                la[j][0] = fmaf(xc[j][d], wq2.x, la[j][0]);
                la[j][1] = fmaf(xc[j][d], wq2.y, la[j][1]);
                la[j][2] = fmaf(xc[j][d], wq2.z, la[j][2]);
            }
            #pragma unroll
            for (int r = 0; r < 5; ++r) {
                const v4f wg = W4[OFF_G1/4 + k*5 + r];
                #pragma unroll
                for (int j = 0; j < 4; ++j) {
                    h[j][4*r+0] = fmaf(xc[j][d], wg.x, h[j][4*r+0]);
                    h[j][4*r+1] = fmaf(xc[j][d], wg.y, h[j][4*r+1]);
                    h[j][4*r+2] = fmaf(xc[j][d], wg.z, h[j][4*r+2]);
                    h[j][4*r+3] = fmaf(xc[j][d], wg.w, h[j][4*r+3]);
                }
            }
            #pragma unroll
            for (int r = 0; r < 5; ++r) {
                const v4f wp = W4[OFF_P2/4 + k*5 + r];
                #pragma unroll
                for (int j = 0; j < 4; ++j) {
                    g[j][4*r+0] = fmaf(xc[j][d], wp.x, g[j][4*r+0]);
                    g[j][4*r+1] = fmaf(xc[j][d], wp.y, g[j][4*r+1]);
                    g[j][4*r+2] = fmaf(xc[j][d], wp.z, g[j][4*r+2]);
                    g[j][4*r+3] = fmaf(xc[j][d], wp.w, g[j][4*r+3]);
                }
            }
        }
    }

    // relu h
    #pragma unroll
    for (int j = 0; j < 4; ++j)
        #pragma unroll
        for (int i = 0; i < 20; ++i) h[j][i] = fmaxf(h[j][i], 0.f);

    // ---- loop2 (fully unrolled): g += h@P1 ; la += h@Q1T ----
    #pragma unroll
    for (int k = 0; k < 20; ++k) {
        const v4f wq1 = W4[OFF_Q1T/4 + k];
        #pragma unroll
        for (int j = 0; j < 4; ++j) {
            la[j][0] = fmaf(h[j][k], wq1.x, la[j][0]);
            la[j][1] = fmaf(h[j][k], wq1.y, la[j][1]);
            la[j][2] = fmaf(h[j][k], wq1.z, la[j][2]);
        }
        #pragma unroll
        for (int r = 0; r < 5; ++r) {
            const v4f wp = W4[OFF_P1/4 + k*5 + r];
            #pragma unroll
            for (int j = 0; j < 4; ++j) {
                g[j][4*r+0] = fmaf(h[j][k], wp.x, g[j][4*r+0]);
                g[j][4*r+1] = fmaf(h[j][k], wp.y, g[j][4*r+1]);
                g[j][4*r+2] = fmaf(h[j][k], wp.z, g[j][4*r+2]);
                g[j][4*r+3] = fmaf(h[j][k], wp.w, g[j][4*r+3]);
            }
        }
    }

    // relu g
    #pragma unroll
    for (int j = 0; j < 4; ++j)
        #pragma unroll
        for (int i = 0; i < 20; ++i) g[j][i] = fmaxf(g[j][i], 0.f);

    // ---- loop3 (fully unrolled): la += g@M2T ----
    #pragma unroll
    for (int k = 0; k < 20; ++k) {
        const v4f wm = W4[OFF_M2T/4 + k];
        #pragma unroll
        for (int j = 0; j < 4; ++j) {
            la[j][0] = fmaf(g[j][k], wm.x, la[j][0]);
            la[j][1] = fmaf(g[j][k], wm.y, la[j][1]);
            la[j][2] = fmaf(g[j][k], wm.z, la[j][2]);
        }
    }

    // softmax per token + vectorized store (12 consecutive floats, 16B-aligned)
    float p[12];
    #pragma unroll
    for (int j = 0; j < 4; ++j) {
        const float m = fmaxf(fmaxf(la[j][0], la[j][1]), la[j][2]);
        const float e0 = __expf(la[j][0] - m);
        const float e1 = __expf(la[j][1] - m);
        const float e2 = __expf(la[j][2] - m);
        const float r = 1.f / (e0 + e1 + e2);
        p[3*j+0] = e0 * r; p[3*j+1] = e1 * r; p[3*j+2] = e2 * r;
    }
    float4* op = reinterpret_cast<float4*>(out + (size_t)t0 * 3);
    op[0] = make_float4(p[0], p[1], p[2], p[3]);
    op[1] = make_float4(p[4], p[5], p[6], p[7]);
    op[2] = make_float4(p[8], p[9], p[10], p[11]);
}

extern "C" void kernel_launch(void* const* d_in, const int* in_sizes, int n_in,
                              void* d_out, int out_size, void* d_ws, size_t ws_size,
                              hipStream_t stream) {
    const float* X    = (const float*)d_in[0];
    // d_in[1]=Wq, d_in[2]=Wk: dead (softmax over singleton axis == 1)
    const float* Wv   = (const float*)d_in[3];
    const float* Wres = (const float*)d_in[4];
    const float* W1   = (const float*)d_in[5];
    const float* b1   = (const float*)d_in[6];
    const float* W2   = (const float*)d_in[7];
    const float* b2   = (const float*)d_in[8];
    const float* W3   = (const float*)d_in[9];
    const float* b3   = (const float*)d_in[10];
    const float* Wc   = (const float*)d_in[11];
    const float* bc   = (const float*)d_in[12];
    float* out = (float*)d_out;
    float* W   = (float*)d_ws;

    const int S = in_sizes[0] / 20;

    prep_kernel<<<1, 256, 0, stream>>>(Wv, Wres, W1, b1, W2, b2, W3, b3, Wc, bc, W);

    const int nthreads = S / 4;                 // S = 1048576 divides evenly
    const int block = 256;
    const int grid = (nthreads + block - 1) / block;
    fwd_kernel<<<grid, block, 0, stream>>>(X, W, out, S);
}

// Round 4
// 172.539 us; speedup vs baseline: 1.5038x; 1.5038x over previous
//
#include <hip/hip_runtime.h>
#include <math.h>

// Folded model (exact algebra, per-token):
//   h      = relu(x @ G1 + b11)                      [400 MACs]
//   g      = relu(h @ P1 + x @ P2 + f2)              [800 MACs]
//   logits = g @ M2 + h @ Q1 + x @ Q2 + f3           [180 MACs]
//   out    = softmax(logits)
// Logits weights stored TRANSPOSED and c-padded to 4 (M2T/Q1T/Q2T: [20][4])
// so each loop reads one v4 per k for the logits contribution.

// d_ws layout (float offsets), 16B-aligned rows
#define OFF_G1   0      // [20][20] k-major
#define OFF_P1   400    // [20][20] m'-major
#define OFF_P2   800    // [20][20] k-major
#define OFF_M2T  1200   // [20][4]  M2T[m][c] = sum_p Wc[c][p]*W2_1[p][m]
#define OFF_Q1T  1280   // [20][4]  Q1T[k][c]
#define OFF_Q2T  1360   // [20][4]  Q2T[k][c]
#define OFF_B11  1440   // [20]
#define OFF_F2   1460   // [20]
#define OFF_F3   1480   // [3] + pad
#define NWTOT    1484

__global__ void prep_kernel(const float* __restrict__ Wv, const float* __restrict__ Wres,
                            const float* __restrict__ W1, const float* __restrict__ b1,
                            const float* __restrict__ W2, const float* __restrict__ b2,
                            const float* __restrict__ W3, const float* __restrict__ b3,
                            const float* __restrict__ Wc, const float* __restrict__ bc,
                            float* __restrict__ W) {
    __shared__ float G2[400];   // [i][m]
    __shared__ float M3[60];    // [i][c]
    __shared__ float e1[20];
    const int tid = threadIdx.x;
    // ---- phase A: layer-1 folds ----
    for (int idx = tid; idx < 480; idx += 256) {
        if (idx < 400) {
            const int i = idx / 20, m = idx % 20;
            float s = 0.f;
            for (int j = 0; j < 20; ++j)
                s = fmaf(Wv[400 + j*20 + i] + Wres[400 + i*20 + j], W1[400 + m*20 + j], s);
            G2[idx] = s;
        } else if (idx < 460) {
            const int r = idx - 400, i = r / 3, c = r % 3;
            float s = 0.f;
            for (int p = 0; p < 20; ++p)
                s = fmaf(Wc[c*20 + p], W3[400 + p*20 + i], s);
            M3[r] = s;
        } else {
            const int j = idx - 460;
            e1[j] = b2[j] + b3[j];
        }
    }
    __syncthreads();
    // ---- phase B: final folded weights → d_ws ----
    for (int idx = tid; idx < NWTOT; idx += 256) {
        float s = 0.f;
        if (idx < 400) {                       // G1[k][m]
            const int k = idx / 20, m = idx % 20;
            for (int j = 0; j < 20; ++j)
                s = fmaf(Wv[j*20 + k] + Wres[k*20 + j], W1[m*20 + j], s);
        } else if (idx < 800) {                // P1[m'][m]
            const int r = idx - 400, mp = r / 20, m = r % 20;
            for (int i = 0; i < 20; ++i)
                s = fmaf(W2[i*20 + mp], G2[i*20 + m], s);
        } else if (idx < 1200) {               // P2[k][m]
            const int r = idx - 800, k = r / 20, m = r % 20;
            for (int i = 0; i < 20; ++i)
                s = fmaf(W3[i*20 + k], G2[i*20 + m], s);
        } else if (idx < 1280) {               // M2T[m][c]
            const int r = idx - 1200, m = r / 4, c = r % 4;
            if (c < 3)
                for (int p = 0; p < 20; ++p)
                    s = fmaf(Wc[c*20 + p], W2[400 + p*20 + m], s);
        } else if (idx < 1360) {               // Q1T[k][c]
            const int r = idx - 1280, k = r / 4, c = r % 4;
            if (c < 3)
                for (int i = 0; i < 20; ++i)
                    s = fmaf(W2[i*20 + k], M3[i*3 + c], s);
        } else if (idx < 1440) {               // Q2T[k][c]
            const int r = idx - 1360, k = r / 4, c = r % 4;
            if (c < 3)
                for (int i = 0; i < 20; ++i)
                    s = fmaf(W3[i*20 + k], M3[i*3 + c], s);
        } else if (idx < 1460) {               // b11
            s = b1[idx - 1440];
        } else if (idx < 1480) {               // f2
            const int m = idx - 1460;
            s = b1[20 + m];
            for (int i = 0; i < 20; ++i)
                s = fmaf(e1[i], G2[i*20 + m], s);
        } else {                               // f3 (+1 pad = 0)
            const int c = idx - 1480;
            if (c < 3) {
                s = bc[c];
                for (int p = 0; p < 20; ++p)
                    s = fmaf(Wc[c*20 + p], b2[20 + p] + b3[20 + p], s);
                for (int i = 0; i < 20; ++i)
                    s = fmaf(e1[i], M3[i*3 + c], s);
            }
        }
        W[idx] = s;
    }
}

// T=1, chunk-wise x, SMEM weights. The 4-round lesson: the allocator remats/
// reloads rather than granting the live set (got 64/68/36/128 vs need
// 126/126/80/190) — so make the live set fit the FRUGAL target instead of
// fighting it. x is consumed 4 elements at a time inside loop1 (h += x_k*G1,
// g += x_k*P2, la += x_k*Q2T) and is DEAD afterwards: peak live =
// h[20]+g[20]+la[3]+xchunk[4]+addr ~ 58 < 64 VGPRs. Weights ride the scalar
// pipe (s_load, zero VGPR/LDS cost). All register arrays statically indexed.
typedef float v4f __attribute__((ext_vector_type(4)));
typedef const __attribute__((address_space(4))) v4f  c4f_t;
typedef const __attribute__((address_space(4))) float cfl_t;

__global__ __launch_bounds__(256, 6) void fwd_kernel(const float* __restrict__ X,
                                                     const float* __restrict__ Wg,
                                                     float* __restrict__ out, int ntok) {
    c4f_t* W4 = (c4f_t*)(unsigned long long)Wg;
    cfl_t* Wf = (cfl_t*)(unsigned long long)Wg;

    const int tid = blockIdx.x * blockDim.x + threadIdx.x;
    if (tid >= ntok) return;
    const float4* xp = reinterpret_cast<const float4*>(X + (size_t)tid * 20);

    float h[20], g[20], la[3];

    // init: h = b11, g = f2, la = f3
    #pragma unroll
    for (int q = 0; q < 5; ++q) {
        const v4f b = W4[OFF_B11/4 + q];
        const v4f f = W4[OFF_F2/4 + q];
        h[4*q+0] = b.x; h[4*q+1] = b.y; h[4*q+2] = b.z; h[4*q+3] = b.w;
        g[4*q+0] = f.x; g[4*q+1] = f.y; g[4*q+2] = f.z; g[4*q+3] = f.w;
    }
    la[0] = Wf[OFF_F3 + 0]; la[1] = Wf[OFF_F3 + 1]; la[2] = Wf[OFF_F3 + 2];

    // ---- loop1: h += x@G1 ; g += x@P2 ; la += x@Q2T  (x chunk-wise, then dead)
    #pragma unroll
    for (int q = 0; q < 5; ++q) {
        const float4 xv = xp[q];
        float xc[4];
        xc[0] = xv.x; xc[1] = xv.y; xc[2] = xv.z; xc[3] = xv.w;
        #pragma unroll
        for (int d = 0; d < 4; ++d) {
            const int k = 4*q + d;
            const float xk = xc[d];
            const v4f wq2 = W4[OFF_Q2T/4 + k];
            la[0] = fmaf(xk, wq2.x, la[0]);
            la[1] = fmaf(xk, wq2.y, la[1]);
            la[2] = fmaf(xk, wq2.z, la[2]);
            #pragma unroll
            for (int r = 0; r < 5; ++r) {
                const v4f wg = W4[OFF_G1/4 + k*5 + r];
                h[4*r+0] = fmaf(xk, wg.x, h[4*r+0]);
                h[4*r+1] = fmaf(xk, wg.y, h[4*r+1]);
                h[4*r+2] = fmaf(xk, wg.z, h[4*r+2]);
                h[4*r+3] = fmaf(xk, wg.w, h[4*r+3]);
            }
            #pragma unroll
            for (int r = 0; r < 5; ++r) {
                const v4f wp = W4[OFF_P2/4 + k*5 + r];
                g[4*r+0] = fmaf(xk, wp.x, g[4*r+0]);
                g[4*r+1] = fmaf(xk, wp.y, g[4*r+1]);
                g[4*r+2] = fmaf(xk, wp.z, g[4*r+2]);
                g[4*r+3] = fmaf(xk, wp.w, g[4*r+3]);
            }
        }
    }

    #pragma unroll
    for (int i = 0; i < 20; ++i) h[i] = fmaxf(h[i], 0.f);

    // ---- loop2: g += h@P1 ; la += h@Q1T ----
    #pragma unroll
    for (int k = 0; k < 20; ++k) {
        const float hk = h[k];
        const v4f wq1 = W4[OFF_Q1T/4 + k];
        la[0] = fmaf(hk, wq1.x, la[0]);
        la[1] = fmaf(hk, wq1.y, la[1]);
        la[2] = fmaf(hk, wq1.z, la[2]);
        #pragma unroll
        for (int r = 0; r < 5; ++r) {
            const v4f wp = W4[OFF_P1/4 + k*5 + r];
            g[4*r+0] = fmaf(hk, wp.x, g[4*r+0]);
            g[4*r+1] = fmaf(hk, wp.y, g[4*r+1]);
            g[4*r+2] = fmaf(hk, wp.z, g[4*r+2]);
            g[4*r+3] = fmaf(hk, wp.w, g[4*r+3]);
        }
    }

    #pragma unroll
    for (int i = 0; i < 20; ++i) g[i] = fmaxf(g[i], 0.f);

    // ---- loop3: la += g@M2T ----
    #pragma unroll
    for (int k = 0; k < 20; ++k) {
        const float gk = g[k];
        const v4f wm = W4[OFF_M2T/4 + k];
        la[0] = fmaf(gk, wm.x, la[0]);
        la[1] = fmaf(gk, wm.y, la[1]);
        la[2] = fmaf(gk, wm.z, la[2]);
    }

    // softmax + store (3 floats per token)
    const float m = fmaxf(fmaxf(la[0], la[1]), la[2]);
    const float e0 = __expf(la[0] - m), e1 = __expf(la[1] - m), e2 = __expf(la[2] - m);
    const float r = 1.f / (e0 + e1 + e2);
    float* o = out + (size_t)tid * 3;
    o[0] = e0 * r;
    o[1] = e1 * r;
    o[2] = e2 * r;
}

extern "C" void kernel_launch(void* const* d_in, const int* in_sizes, int n_in,
                              void* d_out, int out_size, void* d_ws, size_t ws_size,
                              hipStream_t stream) {
    const float* X    = (const float*)d_in[0];
    // d_in[1]=Wq, d_in[2]=Wk: dead (softmax over singleton axis == 1)
    const float* Wv   = (const float*)d_in[3];
    const float* Wres = (const float*)d_in[4];
    const float* W1   = (const float*)d_in[5];
    const float* b1   = (const float*)d_in[6];
    const float* W2   = (const float*)d_in[7];
    const float* b2   = (const float*)d_in[8];
    const float* W3   = (const float*)d_in[9];
    const float* b3   = (const float*)d_in[10];
    const float* Wc   = (const float*)d_in[11];
    const float* bc   = (const float*)d_in[12];
    float* out = (float*)d_out;
    float* W   = (float*)d_ws;

    const int S = in_sizes[0] / 20;

    prep_kernel<<<1, 256, 0, stream>>>(Wv, Wres, W1, b1, W2, b2, W3, b3, Wc, bc, W);

    const int block = 256;
    const int grid = (S + block - 1) / block;
    fwd_kernel<<<grid, block, 0, stream>>>(X, W, out, S);
}